// Round 1
// baseline (487.044 us; speedup 1.0000x reference)
//
#include <hip/hip_runtime.h>

// ---------------- workspace layout (floats) ----------------
#define N_P1    (512*16*50*32)          // 13,107,200
#define N_FEAT  (512*12800)             // 6,553,600
#define N_PART  (16*512*256)            // 2,097,152
#define N_CUR1  (512*256)

#define WS_P1    0
#define WS_FEAT  (WS_P1 + N_P1)
#define WS_PART  (WS_FEAT + N_FEAT)
#define WS_CUR1  (WS_PART + N_PART)
#define WS_W1F   (WS_CUR1 + N_CUR1)     // 144 folded conv1 weights
#define WS_SH1   (WS_W1F + 144)         // 16
#define WS_W2F   (WS_SH1 + 16)          // 4608 folded conv2 weights
#define WS_SH2   (WS_W2F + 4608)        // 32

// ---------------- prep: fold BN + conv bias into weights ----------------
__global__ void prep_kernel(const float* __restrict__ w1, const float* __restrict__ cb1,
                            const float* __restrict__ g1, const float* __restrict__ bb1,
                            const float* __restrict__ m1, const float* __restrict__ v1,
                            const float* __restrict__ w2, const float* __restrict__ cb2,
                            const float* __restrict__ g2, const float* __restrict__ bb2,
                            const float* __restrict__ m2, const float* __restrict__ v2,
                            float* __restrict__ ws) {
    int tid = threadIdx.x;
    for (int i = tid; i < 144; i += 256) {
        int c = i / 9;
        float inv = g1[c] * rsqrtf(v1[c] + 1e-5f);
        ws[WS_W1F + i] = w1[i] * inv;
    }
    if (tid < 16) {
        float inv = g1[tid] * rsqrtf(v1[tid] + 1e-5f);
        ws[WS_SH1 + tid] = cb1[tid] * inv + bb1[tid] - m1[tid] * inv;
    }
    for (int i = tid; i < 4608; i += 256) {
        int c = i / 144;
        float inv = g2[c] * rsqrtf(v2[c] + 1e-5f);
        ws[WS_W2F + i] = w2[i] * inv;
    }
    if (tid < 32) {
        float inv = g2[tid] * rsqrtf(v2[tid] + 1e-5f);
        ws[WS_SH2 + tid] = cb2[tid] * inv + bb2[tid] - m2[tid] * inv;
    }
}

// ---------------- conv1: mean over T + conv3x3 + (folded bn) + relu + pool ----------------
// one block per image; image (100x64) + halo in LDS
__global__ __launch_bounds__(256) void conv1_kernel(const float* __restrict__ x,
                                                    const float* __restrict__ w1f,
                                                    const float* __restrict__ sh1,
                                                    float* __restrict__ p1) {
    __shared__ float xs[102 * 66];
    __shared__ float w1s[144];
    __shared__ float sh1s[16];
    const int b = blockIdx.x;
    const int tid = threadIdx.x;
    if (tid < 144) w1s[tid] = w1f[tid];
    if (tid < 16)  sh1s[tid] = sh1[tid];
    for (int i = tid; i < 102 * 66; i += 256) xs[i] = 0.f;
    __syncthreads();
    // interior: h 0..99 -> xs rows 1..100, w chunks of 4
    for (int i = tid; i < 100 * 16; i += 256) {
        int h = i >> 4, cq = i & 15;
        const float* px = x + (size_t)b * 6400 + h * 64 + cq * 4;
        float4 s = make_float4(0.f, 0.f, 0.f, 0.f);
        #pragma unroll 5
        for (int t = 0; t < 25; ++t) {
            float4 v = *(const float4*)(px + (size_t)t * 512 * 6400);
            s.x += v.x; s.y += v.y; s.z += v.z; s.w += v.w;
        }
        const float sc = 1.0f / 25.0f;
        float* d = &xs[(h + 1) * 66 + 1 + cq * 4];
        d[0] = s.x * sc; d[1] = s.y * sc; d[2] = s.z * sc; d[3] = s.w * sc;
    }
    __syncthreads();
    for (int pos = tid; pos < 1600; pos += 256) {
        int ph = pos >> 5, pw = pos & 31;
        float win[4][4];
        #pragma unroll
        for (int a = 0; a < 4; ++a)
            #pragma unroll
            for (int c2 = 0; c2 < 4; ++c2)
                win[a][c2] = xs[(2 * ph + a) * 66 + 2 * pw + c2];
        #pragma unroll 1
        for (int c = 0; c < 16; ++c) {
            float s00 = 0.f, s01 = 0.f, s10 = 0.f, s11 = 0.f;
            #pragma unroll
            for (int dh = 0; dh < 3; ++dh)
                #pragma unroll
                for (int dw = 0; dw < 3; ++dw) {
                    float w = w1s[c * 9 + dh * 3 + dw];
                    s00 = fmaf(win[dh][dw],       w, s00);
                    s01 = fmaf(win[dh][dw + 1],   w, s01);
                    s10 = fmaf(win[dh + 1][dw],   w, s10);
                    s11 = fmaf(win[dh + 1][dw + 1], w, s11);
                }
            float m = fmaxf(fmaxf(s00, s01), fmaxf(s10, s11));
            float val = fmaxf(m + sh1s[c], 0.f);
            p1[(((size_t)b * 16 + c) * 50 + ph) * 32 + pw] = val;
        }
    }
}

// ---------------- conv2: conv3x3(16->32) + (folded bn) + relu + pool ----------------
// grid = 512 images x 4 row-strips (8 pool rows each). block 256:
// tid -> chg(16) x phl(8) x half(2); each thread: 2 out-ch, 2 conv rows, 16 conv cols.
__global__ __launch_bounds__(256) void conv2_kernel(const float* __restrict__ p1,
                                                    const float* __restrict__ w2f,
                                                    const float* __restrict__ sh2,
                                                    float* __restrict__ feat) {
    __shared__ float ins[16 * 18 * 36];   // [ci][row -1..16][col -1..34]
    __shared__ float wl[16 * 9 * 32];     // [ci][tap][c] for conflict-free reads
    __shared__ float sh2s[32];
    const int bid = blockIdx.x;
    const int b = bid >> 2, s = bid & 3;
    const int tid = threadIdx.x;
    const int chg = tid & 15, phl = (tid >> 4) & 7, half = tid >> 7;
    const int ph = s * 8 + phl;

    // load input strip (global input rows s*16-1 .. s*16+16, cols -1..34)
    for (int i = tid; i < 16 * 18 * 36; i += 256) {
        int ci = i / 648, rem = i % 648;
        int lr = rem / 36, lc = rem % 36;
        int gr = s * 16 - 1 + lr, gc = lc - 1;
        float v = 0.f;
        if (gr >= 0 && gr < 50 && gc >= 0 && gc < 32)
            v = p1[(((size_t)b * 16 + ci) * 50 + gr) * 32 + gc];
        ins[i] = v;
    }
    // weights transposed: wl[(ci*9+t)*32 + c] = w2f[c*144 + ci*9 + t]
    for (int i = tid; i < 4608; i += 256) {
        int c = i / 144, rem = i % 144;  // rem = ci*9 + t
        wl[rem * 32 + c] = w2f[i];
    }
    if (tid < 32) sh2s[tid] = sh2[tid];
    __syncthreads();

    if (ph < 25) {
        float acc[2][2][16];
        #pragma unroll
        for (int a = 0; a < 2; ++a)
            #pragma unroll
            for (int r = 0; r < 2; ++r)
                #pragma unroll
                for (int xx = 0; xx < 16; ++xx) acc[a][r][xx] = 0.f;
        const int xb = half * 16;
        #pragma unroll 1
        for (int ci = 0; ci < 16; ++ci) {
            float2 wv[9];
            #pragma unroll
            for (int t = 0; t < 9; ++t)
                wv[t] = *(const float2*)&wl[(ci * 9 + t) * 32 + 2 * chg];
            #pragma unroll
            for (int lr4 = 0; lr4 < 4; ++lr4) {
                const float* row = &ins[(ci * 18 + (2 * phl + lr4)) * 36 + xb];
                float v[18];
                float4 t0 = *(const float4*)&row[0];
                float4 t1 = *(const float4*)&row[4];
                float4 t2 = *(const float4*)&row[8];
                float4 t3 = *(const float4*)&row[12];
                v[0]=t0.x; v[1]=t0.y; v[2]=t0.z; v[3]=t0.w;
                v[4]=t1.x; v[5]=t1.y; v[6]=t1.z; v[7]=t1.w;
                v[8]=t2.x; v[9]=t2.y; v[10]=t2.z; v[11]=t2.w;
                v[12]=t3.x; v[13]=t3.y; v[14]=t3.z; v[15]=t3.w;
                v[16] = row[16]; v[17] = row[17];
                #pragma unroll
                for (int a = 0; a < 2; ++a) {
                    const int dh = lr4 - a;
                    if (dh >= 0 && dh <= 2) {
                        #pragma unroll
                        for (int dw = 0; dw < 3; ++dw) {
                            float w0 = wv[dh * 3 + dw].x;
                            float w1 = wv[dh * 3 + dw].y;
                            #pragma unroll
                            for (int xx = 0; xx < 16; ++xx) {
                                acc[0][a][xx] = fmaf(v[xx + dw], w0, acc[0][a][xx]);
                                acc[1][a][xx] = fmaf(v[xx + dw], w1, acc[1][a][xx]);
                            }
                        }
                    }
                }
            }
        }
        #pragma unroll
        for (int ch = 0; ch < 2; ++ch) {
            const int c = 2 * chg + ch;
            const float sh = sh2s[c];
            #pragma unroll
            for (int pwl = 0; pwl < 8; ++pwl) {
                float m = fmaxf(fmaxf(acc[ch][0][2 * pwl], acc[ch][0][2 * pwl + 1]),
                                fmaxf(acc[ch][1][2 * pwl], acc[ch][1][2 * pwl + 1]));
                float val = fmaxf(m + sh, 0.f);
                feat[(((size_t)b * 32 + c) * 25 + ph) * 16 + half * 8 + pwl] = val;
            }
        }
    }
}

// ---------------- fc1: split-K f32 GEMM, partials to ws ----------------
// grid (8, 4, 16): 64x64 C-tile, K chunk 800. 256 threads, 4x4 micro-tile.
__global__ __launch_bounds__(256) void fc1_kernel(const float* __restrict__ feat,
                                                  const float* __restrict__ w,
                                                  float* __restrict__ part) {
    __shared__ float As[16 * 68];
    __shared__ float Bs[16 * 68];
    const int bx = blockIdx.x, by = blockIdx.y, bz = blockIdx.z;
    const int tid = threadIdx.x;
    const int tm = tid >> 4, tn = tid & 15;
    const int r = tid >> 2, cq = tid & 3;
    const int m0 = bx * 64, n0 = by * 64;
    const size_t aBase = (size_t)(m0 + r) * 12800 + bz * 800;
    const size_t bBase = (size_t)(n0 + r) * 12800 + bz * 800;
    float acc[4][4];
    #pragma unroll
    for (int i = 0; i < 4; ++i)
        #pragma unroll
        for (int j = 0; j < 4; ++j) acc[i][j] = 0.f;

    for (int kt = 0; kt < 50; ++kt) {
        float4 a4 = *(const float4*)(feat + aBase + kt * 16 + cq * 4);
        float4 b4 = *(const float4*)(w    + bBase + kt * 16 + cq * 4);
        __syncthreads();
        As[(cq * 4 + 0) * 68 + r] = a4.x; As[(cq * 4 + 1) * 68 + r] = a4.y;
        As[(cq * 4 + 2) * 68 + r] = a4.z; As[(cq * 4 + 3) * 68 + r] = a4.w;
        Bs[(cq * 4 + 0) * 68 + r] = b4.x; Bs[(cq * 4 + 1) * 68 + r] = b4.y;
        Bs[(cq * 4 + 2) * 68 + r] = b4.z; Bs[(cq * 4 + 3) * 68 + r] = b4.w;
        __syncthreads();
        #pragma unroll
        for (int kk = 0; kk < 16; ++kk) {
            float4 av = *(const float4*)&As[kk * 68 + tm * 4];
            float4 bv = *(const float4*)&Bs[kk * 68 + tn * 4];
            float a_[4] = {av.x, av.y, av.z, av.w};
            float b_[4] = {bv.x, bv.y, bv.z, bv.w};
            #pragma unroll
            for (int i = 0; i < 4; ++i)
                #pragma unroll
                for (int j = 0; j < 4; ++j)
                    acc[i][j] = fmaf(a_[i], b_[j], acc[i][j]);
        }
    }
    #pragma unroll
    for (int i = 0; i < 4; ++i) {
        float4 o = make_float4(acc[i][0], acc[i][1], acc[i][2], acc[i][3]);
        *(float4*)&part[(size_t)bz * 131072 + (size_t)(m0 + tm * 4 + i) * 256 + n0 + tn * 4] = o;
    }
}

// ---------------- reduce partials + bias -> cur1 ----------------
__global__ __launch_bounds__(256) void reduce_kernel(const float* __restrict__ part,
                                                     const float* __restrict__ fc1b,
                                                     float* __restrict__ cur1) {
    int i = blockIdx.x * 256 + threadIdx.x;  // 131072 total
    int n = i & 255;
    float s = fc1b[n];
    #pragma unroll
    for (int z = 0; z < 16; ++z) s += part[(size_t)z * 131072 + i];
    cur1[i] = s;
}

// ---------------- LIF scan: 25 steps, fc2 + fc3, spikes ----------------
// block = 128 threads = 2 waves = 2 batch rows. 256 blocks. fc2_w^T + fc3_w^T in LDS.
__global__ __launch_bounds__(128) void scan_kernel(const float* __restrict__ cur1,
                                                   const float* __restrict__ w2g,
                                                   const float* __restrict__ b2g,
                                                   const float* __restrict__ w3g,
                                                   const float* __restrict__ b3g,
                                                   const float* __restrict__ pb1,
                                                   const float* __restrict__ pb2,
                                                   const float* __restrict__ pb3,
                                                   float* __restrict__ out) {
    __shared__ float w2T[256 * 128];   // [k][j]
    __shared__ float w3T[128 * 36];    // [k][j], padded
    __shared__ float spk1L[2][256];
    __shared__ float spk2L[2][128];
    const int tid = threadIdx.x;
    const int row = tid >> 6, lane = tid & 63;
    const int b = blockIdx.x * 2 + row;
    for (int i = tid; i < 32768; i += 128) { int j = i >> 8, k = i & 255; w2T[k * 128 + j] = w2g[i]; }
    for (int i = tid; i < 4480;  i += 128) { int j = i >> 7, k = i & 127; w3T[k * 36 + j] = w3g[i]; }
    __syncthreads();
    const float be1 = fminf(fmaxf(pb1[0], 0.f), 1.f);
    const float be2 = fminf(fmaxf(pb2[0], 0.f), 1.f);
    const float be3 = fminf(fmaxf(pb3[0], 0.f), 1.f);
    float4 c4 = *(const float4*)&cur1[b * 256 + lane * 4];
    const float cu[4] = {c4.x, c4.y, c4.z, c4.w};
    float2 bias2 = *(const float2*)&b2g[lane * 2];
    float bias3 = (lane < 35) ? b3g[lane] : 0.f;
    float m1[4] = {0.f, 0.f, 0.f, 0.f};
    float m2[2] = {0.f, 0.f};
    float m3 = 0.f;

    for (int t = 0; t < 25; ++t) {
        // layer 1 LIF (input cur1, constant over t)
        float s1[4];
        #pragma unroll
        for (int u = 0; u < 4; ++u) {
            float reset = (m1[u] > 1.f) ? 1.f : 0.f;
            m1[u] = fmaf(be1, m1[u], cu[u]) - reset;
            s1[u] = (m1[u] > 1.f) ? 1.f : 0.f;
        }
        *(float4*)&spk1L[row][lane * 4] = make_float4(s1[0], s1[1], s1[2], s1[3]);
        __syncthreads();
        // fc2: 128 outputs, lane owns j = 2*lane, 2*lane+1
        float a0 = bias2.x, a1 = bias2.y;
        #pragma unroll 4
        for (int k4 = 0; k4 < 64; ++k4) {
            float4 sv = *(const float4*)&spk1L[row][k4 * 4];
            if (sv.x + sv.y + sv.z + sv.w != 0.f) {
                float s_[4] = {sv.x, sv.y, sv.z, sv.w};
                #pragma unroll
                for (int u = 0; u < 4; ++u) {
                    float2 wv = *(const float2*)&w2T[(k4 * 4 + u) * 128 + lane * 2];
                    a0 = fmaf(s_[u], wv.x, a0);
                    a1 = fmaf(s_[u], wv.y, a1);
                }
            }
        }
        // layer 2 LIF
        float in2[2] = {a0, a1};
        float s2[2];
        #pragma unroll
        for (int u = 0; u < 2; ++u) {
            float reset = (m2[u] > 1.f) ? 1.f : 0.f;
            m2[u] = fmaf(be2, m2[u], in2[u]) - reset;
            s2[u] = (m2[u] > 1.f) ? 1.f : 0.f;
        }
        *(float2*)&spk2L[row][lane * 2] = make_float2(s2[0], s2[1]);
        __syncthreads();
        // fc3: 35 outputs on lanes 0..34
        if (lane < 35) {
            float a3 = bias3;
            #pragma unroll 4
            for (int k4 = 0; k4 < 32; ++k4) {
                float4 sv = *(const float4*)&spk2L[row][k4 * 4];
                if (sv.x + sv.y + sv.z + sv.w != 0.f) {
                    float s_[4] = {sv.x, sv.y, sv.z, sv.w};
                    #pragma unroll
                    for (int u = 0; u < 4; ++u)
                        a3 = fmaf(s_[u], w3T[(k4 * 4 + u) * 36 + lane], a3);
                }
            }
            float reset = (m3 > 1.f) ? 1.f : 0.f;
            m3 = fmaf(be3, m3, a3) - reset;
            out[((size_t)t * 512 + b) * 35 + lane] = (m3 > 1.f) ? 1.f : 0.f;
        }
        __syncthreads();
    }
}

// ---------------- launch ----------------
extern "C" void kernel_launch(void* const* d_in, const int* in_sizes, int n_in,
                              void* d_out, int out_size, void* d_ws, size_t ws_size,
                              hipStream_t stream) {
    const float* x     = (const float*)d_in[0];
    const float* c1w   = (const float*)d_in[1];
    const float* c1b   = (const float*)d_in[2];
    const float* bn1g  = (const float*)d_in[3];
    const float* bn1b  = (const float*)d_in[4];
    const float* bn1m  = (const float*)d_in[5];
    const float* bn1v  = (const float*)d_in[6];
    const float* c2w   = (const float*)d_in[7];
    const float* c2b   = (const float*)d_in[8];
    const float* bn2g  = (const float*)d_in[9];
    const float* bn2b  = (const float*)d_in[10];
    const float* bn2m  = (const float*)d_in[11];
    const float* bn2v  = (const float*)d_in[12];
    const float* fc1w  = (const float*)d_in[13];
    const float* fc1b  = (const float*)d_in[14];
    const float* fc2w  = (const float*)d_in[15];
    const float* fc2b  = (const float*)d_in[16];
    const float* fc3w  = (const float*)d_in[17];
    const float* fc3b  = (const float*)d_in[18];
    const float* beta1 = (const float*)d_in[19];
    const float* beta2 = (const float*)d_in[20];
    const float* beta3 = (const float*)d_in[21];
    float* ws  = (float*)d_ws;
    float* out = (float*)d_out;

    prep_kernel<<<1, 256, 0, stream>>>(c1w, c1b, bn1g, bn1b, bn1m, bn1v,
                                       c2w, c2b, bn2g, bn2b, bn2m, bn2v, ws);
    conv1_kernel<<<512, 256, 0, stream>>>(x, ws + WS_W1F, ws + WS_SH1, ws + WS_P1);
    conv2_kernel<<<2048, 256, 0, stream>>>(ws + WS_P1, ws + WS_W2F, ws + WS_SH2, ws + WS_FEAT);
    fc1_kernel<<<dim3(8, 4, 16), 256, 0, stream>>>(ws + WS_FEAT, fc1w, ws + WS_PART);
    reduce_kernel<<<512, 256, 0, stream>>>(ws + WS_PART, fc1b, ws + WS_CUR1);
    scan_kernel<<<256, 128, 0, stream>>>(ws + WS_CUR1, fc2w, fc2b, fc3w, fc3b,
                                         beta1, beta2, beta3, out);
}

// Round 2
// 400.833 us; speedup vs baseline: 1.2151x; 1.2151x over previous
//
#include <hip/hip_runtime.h>

// ---------------- workspace layout (floats) ----------------
#define N_P1    (512*16*50*32)          // 13,107,200
#define N_FEAT  (512*12800)             // 6,553,600
#define N_PART  (32*512*256)            // 4,194,304
#define N_CUR1  (512*256)

#define WS_P1    0
#define WS_FEAT  (WS_P1 + N_P1)
#define WS_PART  (WS_FEAT + N_FEAT)
#define WS_CUR1  (WS_PART + N_PART)
#define WS_W1F   (WS_CUR1 + N_CUR1)     // 144 folded conv1 weights
#define WS_SH1   (WS_W1F + 144)         // 16
#define WS_W2F   (WS_SH1 + 16)          // 4608 folded conv2 weights
#define WS_SH2   (WS_W2F + 4608)        // 32

// ---------------- prep: fold BN + conv bias into weights ----------------
__global__ void prep_kernel(const float* __restrict__ w1, const float* __restrict__ cb1,
                            const float* __restrict__ g1, const float* __restrict__ bb1,
                            const float* __restrict__ m1, const float* __restrict__ v1,
                            const float* __restrict__ w2, const float* __restrict__ cb2,
                            const float* __restrict__ g2, const float* __restrict__ bb2,
                            const float* __restrict__ m2, const float* __restrict__ v2,
                            float* __restrict__ ws) {
    int tid = threadIdx.x;
    for (int i = tid; i < 144; i += 256) {
        int c = i / 9;
        float inv = g1[c] * rsqrtf(v1[c] + 1e-5f);
        ws[WS_W1F + i] = w1[i] * inv;
    }
    if (tid < 16) {
        float inv = g1[tid] * rsqrtf(v1[tid] + 1e-5f);
        ws[WS_SH1 + tid] = cb1[tid] * inv + bb1[tid] - m1[tid] * inv;
    }
    for (int i = tid; i < 4608; i += 256) {
        int c = i / 144;
        float inv = g2[c] * rsqrtf(v2[c] + 1e-5f);
        ws[WS_W2F + i] = w2[i] * inv;
    }
    if (tid < 32) {
        float inv = g2[tid] * rsqrtf(v2[tid] + 1e-5f);
        ws[WS_SH2 + tid] = cb2[tid] * inv + bb2[tid] - m2[tid] * inv;
    }
}

// ---------------- conv1: mean over T + conv3x3 + (folded bn) + relu + pool ----------------
// grid (512 images x 5 row-strips); strip = 10 pool rows = 20 conv rows (+1 halo each side).
__global__ __launch_bounds__(256) void conv1_kernel(const float* __restrict__ x,
                                                    const float* __restrict__ w1f,
                                                    const float* __restrict__ sh1,
                                                    float* __restrict__ p1) {
    __shared__ float xs[22 * 66];
    __shared__ float w1s[144];
    __shared__ float sh1s[16];
    const int b = blockIdx.x, s = blockIdx.y;
    const int tid = threadIdx.x;
    if (tid < 144) w1s[tid] = w1f[tid];
    if (tid < 16)  sh1s[tid] = sh1[tid];
    if (tid < 44)  xs[(tid >> 1) * 66 + (tid & 1) * 65] = 0.f;   // border cols
    const int r0 = s * 20 - 1;
    for (int i = tid; i < 22 * 16; i += 256) {
        int lr = i >> 4, cq = i & 15;
        int gr = r0 + lr;
        float4 sm = make_float4(0.f, 0.f, 0.f, 0.f);
        if (gr >= 0 && gr < 100) {
            const float* px = x + (size_t)b * 6400 + gr * 64 + cq * 4;
            #pragma unroll 5
            for (int t = 0; t < 25; ++t) {
                float4 v = *(const float4*)(px + (size_t)t * 512 * 6400);
                sm.x += v.x; sm.y += v.y; sm.z += v.z; sm.w += v.w;
            }
            const float sc = 1.0f / 25.0f;
            sm.x *= sc; sm.y *= sc; sm.z *= sc; sm.w *= sc;
        }
        float* d = &xs[lr * 66 + 1 + cq * 4];
        d[0] = sm.x; d[1] = sm.y; d[2] = sm.z; d[3] = sm.w;
    }
    __syncthreads();
    for (int pos = tid; pos < 320; pos += 256) {
        int phl = pos >> 5, pw = pos & 31;
        int ph = s * 10 + phl;
        float win[4][4];
        #pragma unroll
        for (int a = 0; a < 4; ++a)
            #pragma unroll
            for (int c2 = 0; c2 < 4; ++c2)
                win[a][c2] = xs[(2 * phl + a) * 66 + 2 * pw + c2];
        #pragma unroll 1
        for (int c = 0; c < 16; ++c) {
            float s00 = 0.f, s01 = 0.f, s10 = 0.f, s11 = 0.f;
            #pragma unroll
            for (int dh = 0; dh < 3; ++dh)
                #pragma unroll
                for (int dw = 0; dw < 3; ++dw) {
                    float w = w1s[c * 9 + dh * 3 + dw];
                    s00 = fmaf(win[dh][dw],         w, s00);
                    s01 = fmaf(win[dh][dw + 1],     w, s01);
                    s10 = fmaf(win[dh + 1][dw],     w, s10);
                    s11 = fmaf(win[dh + 1][dw + 1], w, s11);
                }
            float m = fmaxf(fmaxf(s00, s01), fmaxf(s10, s11));
            float val = fmaxf(m + sh1s[c], 0.f);
            p1[(((size_t)b * 16 + c) * 50 + ph) * 32 + pw] = val;
        }
    }
}

// ---------------- conv2: conv3x3(16->32) + (folded bn) + relu + pool ----------------
__global__ __launch_bounds__(256) void conv2_kernel(const float* __restrict__ p1,
                                                    const float* __restrict__ w2f,
                                                    const float* __restrict__ sh2,
                                                    float* __restrict__ feat) {
    __shared__ float ins[16 * 18 * 36];   // [ci][row -1..16][col -1..34]
    __shared__ float wl[16 * 9 * 32];     // [ci][tap][c]
    __shared__ float sh2s[32];
    const int bid = blockIdx.x;
    const int b = bid >> 2, s = bid & 3;
    const int tid = threadIdx.x;
    const int chg = tid & 15, phl = (tid >> 4) & 7, half = tid >> 7;
    const int ph = s * 8 + phl;

    for (int i = tid; i < 16 * 18 * 36; i += 256) {
        int ci = i / 648, rem = i % 648;
        int lr = rem / 36, lc = rem % 36;
        int gr = s * 16 - 1 + lr, gc = lc - 1;
        float v = 0.f;
        if (gr >= 0 && gr < 50 && gc >= 0 && gc < 32)
            v = p1[(((size_t)b * 16 + ci) * 50 + gr) * 32 + gc];
        ins[i] = v;
    }
    for (int i = tid; i < 4608; i += 256) {
        int c = i / 144, rem = i % 144;
        wl[rem * 32 + c] = w2f[i];
    }
    if (tid < 32) sh2s[tid] = sh2[tid];
    __syncthreads();

    if (ph < 25) {
        float acc[2][2][16];
        #pragma unroll
        for (int a = 0; a < 2; ++a)
            #pragma unroll
            for (int r = 0; r < 2; ++r)
                #pragma unroll
                for (int xx = 0; xx < 16; ++xx) acc[a][r][xx] = 0.f;
        const int xb = half * 16;
        #pragma unroll 1
        for (int ci = 0; ci < 16; ++ci) {
            float2 wv[9];
            #pragma unroll
            for (int t = 0; t < 9; ++t)
                wv[t] = *(const float2*)&wl[(ci * 9 + t) * 32 + 2 * chg];
            #pragma unroll
            for (int lr4 = 0; lr4 < 4; ++lr4) {
                const float* row = &ins[(ci * 18 + (2 * phl + lr4)) * 36 + xb];
                float v[18];
                float4 t0 = *(const float4*)&row[0];
                float4 t1 = *(const float4*)&row[4];
                float4 t2 = *(const float4*)&row[8];
                float4 t3 = *(const float4*)&row[12];
                v[0]=t0.x; v[1]=t0.y; v[2]=t0.z; v[3]=t0.w;
                v[4]=t1.x; v[5]=t1.y; v[6]=t1.z; v[7]=t1.w;
                v[8]=t2.x; v[9]=t2.y; v[10]=t2.z; v[11]=t2.w;
                v[12]=t3.x; v[13]=t3.y; v[14]=t3.z; v[15]=t3.w;
                v[16] = row[16]; v[17] = row[17];
                #pragma unroll
                for (int a = 0; a < 2; ++a) {
                    const int dh = lr4 - a;
                    if (dh >= 0 && dh <= 2) {
                        #pragma unroll
                        for (int dw = 0; dw < 3; ++dw) {
                            float w0 = wv[dh * 3 + dw].x;
                            float w1 = wv[dh * 3 + dw].y;
                            #pragma unroll
                            for (int xx = 0; xx < 16; ++xx) {
                                acc[0][a][xx] = fmaf(v[xx + dw], w0, acc[0][a][xx]);
                                acc[1][a][xx] = fmaf(v[xx + dw], w1, acc[1][a][xx]);
                            }
                        }
                    }
                }
            }
        }
        #pragma unroll
        for (int ch = 0; ch < 2; ++ch) {
            const int c = 2 * chg + ch;
            const float sh = sh2s[c];
            #pragma unroll
            for (int pwl = 0; pwl < 8; ++pwl) {
                float m = fmaxf(fmaxf(acc[ch][0][2 * pwl], acc[ch][0][2 * pwl + 1]),
                                fmaxf(acc[ch][1][2 * pwl], acc[ch][1][2 * pwl + 1]));
                float val = fmaxf(m + sh, 0.f);
                feat[(((size_t)b * 32 + c) * 25 + ph) * 16 + half * 8 + pwl] = val;
            }
        }
    }
}

// ---------------- fc1: split-K f32 GEMM, 128x64 tile, 8x4 micro ----------------
// grid (4, 4, 32): K chunk 400 (25 kt of 16).
__global__ __launch_bounds__(256) void fc1_kernel(const float* __restrict__ feat,
                                                  const float* __restrict__ w,
                                                  float* __restrict__ part) {
    __shared__ float As[16 * 136];
    __shared__ float Bs[16 * 68];
    const int bx = blockIdx.x, by = blockIdx.y, bz = blockIdx.z;
    const int tid = threadIdx.x;
    const int tm = tid >> 4, tn = tid & 15;
    const int r = tid >> 2, cq = tid & 3;
    const int m0 = bx * 128, n0 = by * 64;
    const size_t aBase = (size_t)(m0 + r) * 12800 + bz * 400 + cq * 4;
    const size_t bBase = (size_t)(n0 + r) * 12800 + bz * 400 + cq * 4;
    float acc[8][4];
    #pragma unroll
    for (int i = 0; i < 8; ++i)
        #pragma unroll
        for (int j = 0; j < 4; ++j) acc[i][j] = 0.f;

    for (int kt = 0; kt < 25; ++kt) {
        float4 a0 = *(const float4*)(feat + aBase + kt * 16);
        float4 a1 = *(const float4*)(feat + aBase + (size_t)64 * 12800 + kt * 16);
        float4 b0 = *(const float4*)(w    + bBase + kt * 16);
        __syncthreads();
        As[(cq * 4 + 0) * 136 + r]      = a0.x; As[(cq * 4 + 1) * 136 + r]      = a0.y;
        As[(cq * 4 + 2) * 136 + r]      = a0.z; As[(cq * 4 + 3) * 136 + r]      = a0.w;
        As[(cq * 4 + 0) * 136 + 64 + r] = a1.x; As[(cq * 4 + 1) * 136 + 64 + r] = a1.y;
        As[(cq * 4 + 2) * 136 + 64 + r] = a1.z; As[(cq * 4 + 3) * 136 + 64 + r] = a1.w;
        Bs[(cq * 4 + 0) * 68 + r] = b0.x; Bs[(cq * 4 + 1) * 68 + r] = b0.y;
        Bs[(cq * 4 + 2) * 68 + r] = b0.z; Bs[(cq * 4 + 3) * 68 + r] = b0.w;
        __syncthreads();
        #pragma unroll
        for (int kk = 0; kk < 16; ++kk) {
            float4 av0 = *(const float4*)&As[kk * 136 + tm * 8];
            float4 av1 = *(const float4*)&As[kk * 136 + tm * 8 + 4];
            float4 bv  = *(const float4*)&Bs[kk * 68 + tn * 4];
            float a_[8] = {av0.x, av0.y, av0.z, av0.w, av1.x, av1.y, av1.z, av1.w};
            float b_[4] = {bv.x, bv.y, bv.z, bv.w};
            #pragma unroll
            for (int i = 0; i < 8; ++i)
                #pragma unroll
                for (int j = 0; j < 4; ++j)
                    acc[i][j] = fmaf(a_[i], b_[j], acc[i][j]);
        }
    }
    #pragma unroll
    for (int i = 0; i < 8; ++i) {
        float4 o = make_float4(acc[i][0], acc[i][1], acc[i][2], acc[i][3]);
        *(float4*)&part[(size_t)bz * 131072 + (size_t)(m0 + tm * 8 + i) * 256 + n0 + tn * 4] = o;
    }
}

// ---------------- reduce partials + bias -> cur1 ----------------
__global__ __launch_bounds__(256) void reduce_kernel(const float* __restrict__ part,
                                                     const float* __restrict__ fc1b,
                                                     float* __restrict__ cur1) {
    int i = blockIdx.x * 256 + threadIdx.x;  // 131072 total
    int n = i & 255;
    float s = fc1b[n];
    #pragma unroll
    for (int z = 0; z < 32; ++z) s += part[(size_t)z * 131072 + i];
    cur1[i] = s;
}

// ---------------- LIF scan: 25 steps, fc2 + fc3 ----------------
// block = 128 threads = 2 waves = 2 batch rows; wave-autonomous (no per-step barriers).
__global__ __launch_bounds__(128) void scan_kernel(const float* __restrict__ cur1,
                                                   const float* __restrict__ w2g,
                                                   const float* __restrict__ b2g,
                                                   const float* __restrict__ w3g,
                                                   const float* __restrict__ b3g,
                                                   const float* __restrict__ pb1,
                                                   const float* __restrict__ pb2,
                                                   const float* __restrict__ pb3,
                                                   float* __restrict__ out) {
    __shared__ float w2T[256 * 128];   // [k][j]
    __shared__ float w3T[128 * 36];    // [k][j]
    __shared__ float spk1L[2][256];
    __shared__ float spk2L[2][128];
    const int tid = threadIdx.x;
    const int row = tid >> 6, lane = tid & 63;
    const int b = blockIdx.x * 2 + row;
    for (int i = tid; i < 8192; i += 128) {            // w2: (128,256) row-major
        int j = i >> 6, k4 = i & 63;
        float4 v = *(const float4*)&w2g[j * 256 + k4 * 4];
        w2T[(k4 * 4 + 0) * 128 + j] = v.x; w2T[(k4 * 4 + 1) * 128 + j] = v.y;
        w2T[(k4 * 4 + 2) * 128 + j] = v.z; w2T[(k4 * 4 + 3) * 128 + j] = v.w;
    }
    for (int i = tid; i < 4480; i += 128) { int j = i >> 7, k = i & 127; w3T[k * 36 + j] = w3g[i]; }
    __syncthreads();
    const float be1 = fminf(fmaxf(pb1[0], 0.f), 1.f);
    const float be2 = fminf(fmaxf(pb2[0], 0.f), 1.f);
    const float be3 = fminf(fmaxf(pb3[0], 0.f), 1.f);
    float4 c4 = *(const float4*)&cur1[b * 256 + lane * 4];
    const float cu[4] = {c4.x, c4.y, c4.z, c4.w};
    float2 bias2 = *(const float2*)&b2g[lane * 2];
    float bias3 = (lane < 35) ? b3g[lane] : 0.f;
    float m1[4] = {0.f, 0.f, 0.f, 0.f};
    float m2[2] = {0.f, 0.f};
    float m3 = 0.f;

    for (int t = 0; t < 25; ++t) {
        float s1[4];
        #pragma unroll
        for (int u = 0; u < 4; ++u) {
            float reset = (m1[u] > 1.f) ? 1.f : 0.f;
            m1[u] = fmaf(be1, m1[u], cu[u]) - reset;
            s1[u] = (m1[u] > 1.f) ? 1.f : 0.f;
        }
        *(float4*)&spk1L[row][lane * 4] = make_float4(s1[0], s1[1], s1[2], s1[3]);
        float a0 = bias2.x, a1 = bias2.y;
        #pragma unroll 8
        for (int k4 = 0; k4 < 64; ++k4) {
            float4 sv = *(const float4*)&spk1L[row][k4 * 4];
            float s_[4] = {sv.x, sv.y, sv.z, sv.w};
            #pragma unroll
            for (int u = 0; u < 4; ++u) {
                float2 wv = *(const float2*)&w2T[(k4 * 4 + u) * 128 + lane * 2];
                a0 = fmaf(s_[u], wv.x, a0);
                a1 = fmaf(s_[u], wv.y, a1);
            }
        }
        float s2[2];
        #pragma unroll
        for (int u = 0; u < 2; ++u) {
            float reset = (m2[u] > 1.f) ? 1.f : 0.f;
            m2[u] = fmaf(be2, m2[u], (u == 0 ? a0 : a1)) - reset;
            s2[u] = (m2[u] > 1.f) ? 1.f : 0.f;
        }
        *(float2*)&spk2L[row][lane * 2] = make_float2(s2[0], s2[1]);
        if (lane < 35) {
            float a3 = bias3;
            #pragma unroll 8
            for (int k4 = 0; k4 < 32; ++k4) {
                float4 sv = *(const float4*)&spk2L[row][k4 * 4];
                float s_[4] = {sv.x, sv.y, sv.z, sv.w};
                #pragma unroll
                for (int u = 0; u < 4; ++u)
                    a3 = fmaf(s_[u], w3T[(k4 * 4 + u) * 36 + lane], a3);
            }
            float reset = (m3 > 1.f) ? 1.f : 0.f;
            m3 = fmaf(be3, m3, a3) - reset;
            out[((size_t)t * 512 + b) * 35 + lane] = (m3 > 1.f) ? 1.f : 0.f;
        }
    }
}

// ---------------- launch ----------------
extern "C" void kernel_launch(void* const* d_in, const int* in_sizes, int n_in,
                              void* d_out, int out_size, void* d_ws, size_t ws_size,
                              hipStream_t stream) {
    const float* x     = (const float*)d_in[0];
    const float* c1w   = (const float*)d_in[1];
    const float* c1b   = (const float*)d_in[2];
    const float* bn1g  = (const float*)d_in[3];
    const float* bn1b  = (const float*)d_in[4];
    const float* bn1m  = (const float*)d_in[5];
    const float* bn1v  = (const float*)d_in[6];
    const float* c2w   = (const float*)d_in[7];
    const float* c2b   = (const float*)d_in[8];
    const float* bn2g  = (const float*)d_in[9];
    const float* bn2b  = (const float*)d_in[10];
    const float* bn2m  = (const float*)d_in[11];
    const float* bn2v  = (const float*)d_in[12];
    const float* fc1w  = (const float*)d_in[13];
    const float* fc1b  = (const float*)d_in[14];
    const float* fc2w  = (const float*)d_in[15];
    const float* fc2b  = (const float*)d_in[16];
    const float* fc3w  = (const float*)d_in[17];
    const float* fc3b  = (const float*)d_in[18];
    const float* beta1 = (const float*)d_in[19];
    const float* beta2 = (const float*)d_in[20];
    const float* beta3 = (const float*)d_in[21];
    float* ws  = (float*)d_ws;
    float* out = (float*)d_out;

    prep_kernel<<<1, 256, 0, stream>>>(c1w, c1b, bn1g, bn1b, bn1m, bn1v,
                                       c2w, c2b, bn2g, bn2b, bn2m, bn2v, ws);
    conv1_kernel<<<dim3(512, 5), 256, 0, stream>>>(x, ws + WS_W1F, ws + WS_SH1, ws + WS_P1);
    conv2_kernel<<<2048, 256, 0, stream>>>(ws + WS_P1, ws + WS_W2F, ws + WS_SH2, ws + WS_FEAT);
    fc1_kernel<<<dim3(4, 4, 32), 256, 0, stream>>>(ws + WS_FEAT, fc1w, ws + WS_PART);
    reduce_kernel<<<512, 256, 0, stream>>>(ws + WS_PART, fc1b, ws + WS_CUR1);
    scan_kernel<<<256, 128, 0, stream>>>(ws + WS_CUR1, fc2w, fc2b, fc3w, fc3b,
                                         beta1, beta2, beta3, out);
}

// Round 3
// 348.923 us; speedup vs baseline: 1.3958x; 1.1488x over previous
//
#include <hip/hip_runtime.h>

// ---------------- workspace layout (floats) ----------------
#define N_P1    (512*16*50*32)          // 13,107,200
#define N_FEAT  (512*12800)             // 6,553,600
#define N_PART  (32*512*256)            // 4,194,304

#define WS_P1    0
#define WS_FEAT  (WS_P1 + N_P1)
#define WS_PART  (WS_FEAT + N_FEAT)

// ---------------- conv1: mean over T + conv3x3 + bn-fold + relu + pool ----------------
// grid (512 images x 5 row-strips); strip = 10 pool rows = 20 conv rows (+1 halo each side).
__global__ __launch_bounds__(256) void conv1_kernel(const float* __restrict__ x,
                                                    const float* __restrict__ w1,
                                                    const float* __restrict__ cb1,
                                                    const float* __restrict__ g1,
                                                    const float* __restrict__ bb1,
                                                    const float* __restrict__ m1g,
                                                    const float* __restrict__ v1,
                                                    float* __restrict__ p1) {
    __shared__ float xs[22 * 66];
    __shared__ float w1s[144];
    __shared__ float sh1s[16];
    const int b = blockIdx.x, s = blockIdx.y;
    const int tid = threadIdx.x;
    if (tid < 144) {
        int c = tid / 9;
        float inv = g1[c] * rsqrtf(v1[c] + 1e-5f);
        w1s[tid] = w1[tid] * inv;
    }
    if (tid < 16) {
        float inv = g1[tid] * rsqrtf(v1[tid] + 1e-5f);
        sh1s[tid] = cb1[tid] * inv + bb1[tid] - m1g[tid] * inv;
    }
    if (tid < 44) xs[(tid >> 1) * 66 + (tid & 1) * 65] = 0.f;   // border cols
    const int r0 = s * 20 - 1;
    const size_t TSTR = (size_t)512 * 6400;
    for (int i = tid; i < 22 * 16; i += 256) {
        int lr = i >> 4, cq = i & 15;
        int gr = r0 + lr;
        float4 a0 = make_float4(0.f, 0.f, 0.f, 0.f), a1 = a0, a2 = a0, a3 = a0;
        if (gr >= 0 && gr < 100) {
            const float* px = x + (size_t)b * 6400 + gr * 64 + cq * 4;
            #pragma unroll
            for (int tt = 0; tt < 24; tt += 4) {
                float4 v0 = *(const float4*)(px + (size_t)(tt + 0) * TSTR);
                float4 v1_ = *(const float4*)(px + (size_t)(tt + 1) * TSTR);
                float4 v2_ = *(const float4*)(px + (size_t)(tt + 2) * TSTR);
                float4 v3 = *(const float4*)(px + (size_t)(tt + 3) * TSTR);
                a0.x += v0.x; a0.y += v0.y; a0.z += v0.z; a0.w += v0.w;
                a1.x += v1_.x; a1.y += v1_.y; a1.z += v1_.z; a1.w += v1_.w;
                a2.x += v2_.x; a2.y += v2_.y; a2.z += v2_.z; a2.w += v2_.w;
                a3.x += v3.x; a3.y += v3.y; a3.z += v3.z; a3.w += v3.w;
            }
            float4 v = *(const float4*)(px + (size_t)24 * TSTR);
            a0.x += v.x; a0.y += v.y; a0.z += v.z; a0.w += v.w;
        }
        const float sc = 1.0f / 25.0f;
        float* d = &xs[lr * 66 + 1 + cq * 4];
        d[0] = (a0.x + a1.x + a2.x + a3.x) * sc;
        d[1] = (a0.y + a1.y + a2.y + a3.y) * sc;
        d[2] = (a0.z + a1.z + a2.z + a3.z) * sc;
        d[3] = (a0.w + a1.w + a2.w + a3.w) * sc;
    }
    __syncthreads();
    for (int pos = tid; pos < 320; pos += 256) {
        int phl = pos >> 5, pw = pos & 31;
        int ph = s * 10 + phl;
        float win[4][4];
        #pragma unroll
        for (int a = 0; a < 4; ++a)
            #pragma unroll
            for (int c2 = 0; c2 < 4; ++c2)
                win[a][c2] = xs[(2 * phl + a) * 66 + 2 * pw + c2];
        #pragma unroll 1
        for (int c = 0; c < 16; ++c) {
            float s00 = 0.f, s01 = 0.f, s10 = 0.f, s11 = 0.f;
            #pragma unroll
            for (int dh = 0; dh < 3; ++dh)
                #pragma unroll
                for (int dw = 0; dw < 3; ++dw) {
                    float w = w1s[c * 9 + dh * 3 + dw];
                    s00 = fmaf(win[dh][dw],         w, s00);
                    s01 = fmaf(win[dh][dw + 1],     w, s01);
                    s10 = fmaf(win[dh + 1][dw],     w, s10);
                    s11 = fmaf(win[dh + 1][dw + 1], w, s11);
                }
            float m = fmaxf(fmaxf(s00, s01), fmaxf(s10, s11));
            float val = fmaxf(m + sh1s[c], 0.f);
            p1[(((size_t)b * 16 + c) * 50 + ph) * 32 + pw] = val;
        }
    }
}

// ---------------- conv2: conv3x3(16->32) + bn-fold + relu + pool ----------------
__global__ __launch_bounds__(256) void conv2_kernel(const float* __restrict__ p1,
                                                    const float* __restrict__ w2g,
                                                    const float* __restrict__ cb2,
                                                    const float* __restrict__ g2,
                                                    const float* __restrict__ bb2,
                                                    const float* __restrict__ m2g,
                                                    const float* __restrict__ v2,
                                                    float* __restrict__ feat) {
    __shared__ float ins[16 * 18 * 36];   // [ci][row -1..16][col -1..34]
    __shared__ float wl[16 * 9 * 32];     // [ci][tap][c]
    __shared__ float sh2s[32];
    const int bid = blockIdx.x;
    const int b = bid >> 2, s = bid & 3;
    const int tid = threadIdx.x;
    const int chg = tid & 15, phl = (tid >> 4) & 7, half = tid >> 7;
    const int ph = s * 8 + phl;

    // input strip: 288 (ci,lr) rows, vectorized
    for (int i = tid; i < 288; i += 256) {
        int ci = i / 18, lr = i - ci * 18;
        int gr = s * 16 - 1 + lr;
        float* dst = &ins[(ci * 18 + lr) * 36];
        if (gr >= 0 && gr < 50) {
            const float* src = p1 + (((size_t)b * 16 + ci) * 50 + gr) * 32;
            float4 v0 = *(const float4*)src;                  // gc 0..3
            dst[0] = 0.f; dst[1] = v0.x; dst[2] = v0.y; dst[3] = v0.z;
            #pragma unroll
            for (int q = 1; q < 8; ++q) {
                float4 v = *(const float4*)(src + 4 * q - 1); // gc 4q-1..4q+2
                *(float4*)(dst + 4 * q) = v;
            }
            dst[32] = src[31];
            dst[33] = 0.f; dst[34] = 0.f; dst[35] = 0.f;
        } else {
            #pragma unroll
            for (int q = 0; q < 9; ++q) *(float4*)(dst + 4 * q) = make_float4(0.f, 0.f, 0.f, 0.f);
        }
    }
    // weights transposed + bn-folded: wl[(ci*9+t)*32 + c] = w2g[c*144+ci*9+t]*inv[c]
    for (int i = tid; i < 4608; i += 256) {
        int c = i / 144, rem = i - c * 144;
        float inv = g2[c] * rsqrtf(v2[c] + 1e-5f);
        wl[rem * 32 + c] = w2g[i] * inv;
    }
    if (tid < 32) {
        float inv = g2[tid] * rsqrtf(v2[tid] + 1e-5f);
        sh2s[tid] = cb2[tid] * inv + bb2[tid] - m2g[tid] * inv;
    }
    __syncthreads();

    if (ph < 25) {
        float acc[2][2][16];
        #pragma unroll
        for (int a = 0; a < 2; ++a)
            #pragma unroll
            for (int r = 0; r < 2; ++r)
                #pragma unroll
                for (int xx = 0; xx < 16; ++xx) acc[a][r][xx] = 0.f;
        const int xb = half * 16;
        #pragma unroll 1
        for (int ci = 0; ci < 16; ++ci) {
            float2 wv[9];
            #pragma unroll
            for (int t = 0; t < 9; ++t)
                wv[t] = *(const float2*)&wl[(ci * 9 + t) * 32 + 2 * chg];
            #pragma unroll
            for (int lr4 = 0; lr4 < 4; ++lr4) {
                const float* row = &ins[(ci * 18 + (2 * phl + lr4)) * 36 + xb];
                float v[18];
                float4 t0 = *(const float4*)&row[0];
                float4 t1 = *(const float4*)&row[4];
                float4 t2 = *(const float4*)&row[8];
                float4 t3 = *(const float4*)&row[12];
                v[0]=t0.x; v[1]=t0.y; v[2]=t0.z; v[3]=t0.w;
                v[4]=t1.x; v[5]=t1.y; v[6]=t1.z; v[7]=t1.w;
                v[8]=t2.x; v[9]=t2.y; v[10]=t2.z; v[11]=t2.w;
                v[12]=t3.x; v[13]=t3.y; v[14]=t3.z; v[15]=t3.w;
                v[16] = row[16]; v[17] = row[17];
                #pragma unroll
                for (int a = 0; a < 2; ++a) {
                    const int dh = lr4 - a;
                    if (dh >= 0 && dh <= 2) {
                        #pragma unroll
                        for (int dw = 0; dw < 3; ++dw) {
                            float w0 = wv[dh * 3 + dw].x;
                            float w1 = wv[dh * 3 + dw].y;
                            #pragma unroll
                            for (int xx = 0; xx < 16; ++xx) {
                                acc[0][a][xx] = fmaf(v[xx + dw], w0, acc[0][a][xx]);
                                acc[1][a][xx] = fmaf(v[xx + dw], w1, acc[1][a][xx]);
                            }
                        }
                    }
                }
            }
        }
        #pragma unroll
        for (int ch = 0; ch < 2; ++ch) {
            const int c = 2 * chg + ch;
            const float sh = sh2s[c];
            #pragma unroll
            for (int pwl = 0; pwl < 8; ++pwl) {
                float m = fmaxf(fmaxf(acc[ch][0][2 * pwl], acc[ch][0][2 * pwl + 1]),
                                fmaxf(acc[ch][1][2 * pwl], acc[ch][1][2 * pwl + 1]));
                float val = fmaxf(m + sh, 0.f);
                feat[(((size_t)b * 32 + c) * 25 + ph) * 16 + half * 8 + pwl] = val;
            }
        }
    }
}

// ---------------- fc1: split-K f32 GEMM, 128x128 tile, 8x8 micro ----------------
// grid (4, 2, 32): K chunk 400 (25 kt of 16).
__global__ __launch_bounds__(256) void fc1_kernel(const float* __restrict__ feat,
                                                  const float* __restrict__ w,
                                                  float* __restrict__ part) {
    __shared__ float As[16 * 136];
    __shared__ float Bs[16 * 136];
    const int bx = blockIdx.x, by = blockIdx.y, bz = blockIdx.z;
    const int tid = threadIdx.x;
    const int tm = tid >> 4, tn = tid & 15;
    const int r = tid >> 2, cq = tid & 3;
    const int m0 = bx * 128, n0 = by * 128;
    const size_t aBase = (size_t)(m0 + r) * 12800 + bz * 400 + cq * 4;
    const size_t bBase = (size_t)(n0 + r) * 12800 + bz * 400 + cq * 4;
    float acc[8][8];
    #pragma unroll
    for (int i = 0; i < 8; ++i)
        #pragma unroll
        for (int j = 0; j < 8; ++j) acc[i][j] = 0.f;

    for (int kt = 0; kt < 25; ++kt) {
        float4 a0 = *(const float4*)(feat + aBase + kt * 16);
        float4 a1 = *(const float4*)(feat + aBase + (size_t)64 * 12800 + kt * 16);
        float4 b0 = *(const float4*)(w    + bBase + kt * 16);
        float4 b1 = *(const float4*)(w    + bBase + (size_t)64 * 12800 + kt * 16);
        __syncthreads();
        As[(cq * 4 + 0) * 136 + r]      = a0.x; As[(cq * 4 + 1) * 136 + r]      = a0.y;
        As[(cq * 4 + 2) * 136 + r]      = a0.z; As[(cq * 4 + 3) * 136 + r]      = a0.w;
        As[(cq * 4 + 0) * 136 + 64 + r] = a1.x; As[(cq * 4 + 1) * 136 + 64 + r] = a1.y;
        As[(cq * 4 + 2) * 136 + 64 + r] = a1.z; As[(cq * 4 + 3) * 136 + 64 + r] = a1.w;
        Bs[(cq * 4 + 0) * 136 + r]      = b0.x; Bs[(cq * 4 + 1) * 136 + r]      = b0.y;
        Bs[(cq * 4 + 2) * 136 + r]      = b0.z; Bs[(cq * 4 + 3) * 136 + r]      = b0.w;
        Bs[(cq * 4 + 0) * 136 + 64 + r] = b1.x; Bs[(cq * 4 + 1) * 136 + 64 + r] = b1.y;
        Bs[(cq * 4 + 2) * 136 + 64 + r] = b1.z; Bs[(cq * 4 + 3) * 136 + 64 + r] = b1.w;
        __syncthreads();
        #pragma unroll
        for (int kk = 0; kk < 16; ++kk) {
            float4 av0 = *(const float4*)&As[kk * 136 + tm * 8];
            float4 av1 = *(const float4*)&As[kk * 136 + tm * 8 + 4];
            float4 bv0 = *(const float4*)&Bs[kk * 136 + tn * 8];
            float4 bv1 = *(const float4*)&Bs[kk * 136 + tn * 8 + 4];
            float a_[8] = {av0.x, av0.y, av0.z, av0.w, av1.x, av1.y, av1.z, av1.w};
            float b_[8] = {bv0.x, bv0.y, bv0.z, bv0.w, bv1.x, bv1.y, bv1.z, bv1.w};
            #pragma unroll
            for (int i = 0; i < 8; ++i)
                #pragma unroll
                for (int j = 0; j < 8; ++j)
                    acc[i][j] = fmaf(a_[i], b_[j], acc[i][j]);
        }
    }
    #pragma unroll
    for (int i = 0; i < 8; ++i) {
        float* dst = &part[(size_t)bz * 131072 + (size_t)(m0 + tm * 8 + i) * 256 + n0 + tn * 8];
        *(float4*)dst       = make_float4(acc[i][0], acc[i][1], acc[i][2], acc[i][3]);
        *(float4*)(dst + 4) = make_float4(acc[i][4], acc[i][5], acc[i][6], acc[i][7]);
    }
}

// ---------------- LIF scan: fused fc1-reduce + 25 steps of fc2/fc3 ----------------
// 256 blocks x 128 threads (2 waves). Block owns 2 batch rows, both rows IN-THREAD;
// wave w = k-half. Weights read once per block-step (amortized over 2 rows).
__global__ __launch_bounds__(128) void scan_kernel(const float* __restrict__ part,
                                                   const float* __restrict__ b1g,
                                                   const float* __restrict__ w2g,
                                                   const float* __restrict__ b2g,
                                                   const float* __restrict__ w3g,
                                                   const float* __restrict__ b3g,
                                                   const float* __restrict__ pb1,
                                                   const float* __restrict__ pb2,
                                                   const float* __restrict__ pb3,
                                                   float* __restrict__ out) {
    __shared__ float  w2T[256 * 128];   // [k][j]  128 KB
    __shared__ float  w3T[128 * 36];    // [k][j]
    __shared__ float  spkT[2][256];     // layer-1 spikes per row
    __shared__ float  spk2T[2][128];    // layer-2 spikes per row
    __shared__ float4 red[64];          // fc2 cross-wave partials
    __shared__ float2 red3[64];         // fc3 cross-wave partials
    const int tid = threadIdx.x;
    const int wv = tid >> 6, lane = tid & 63;
    const int b0 = blockIdx.x * 2;
    const int myrow = wv;                       // for LIF-1 / cur1
    // ---- weight preload ----
    for (int i = tid; i < 8192; i += 128) {     // w2 (128,256) -> w2T[k][j]
        int j = i >> 6, k4 = i & 63;
        float4 v = *(const float4*)&w2g[j * 256 + k4 * 4];
        w2T[(k4 * 4 + 0) * 128 + j] = v.x; w2T[(k4 * 4 + 1) * 128 + j] = v.y;
        w2T[(k4 * 4 + 2) * 128 + j] = v.z; w2T[(k4 * 4 + 3) * 128 + j] = v.w;
    }
    for (int i = tid; i < 4480; i += 128) { int j = i >> 7, k = i & 127; w3T[k * 36 + j] = w3g[i]; }
    // ---- fused fc1 partial reduction: cur1 for own row, 4 neurons per thread ----
    float cu[4];
    {
        float4 s = *(const float4*)&b1g[lane * 4];
        const float* p = part + (size_t)(b0 + myrow) * 256 + lane * 4;
        #pragma unroll 8
        for (int z = 0; z < 32; ++z) {
            float4 v = *(const float4*)(p + (size_t)z * 131072);
            s.x += v.x; s.y += v.y; s.z += v.z; s.w += v.w;
        }
        cu[0] = s.x; cu[1] = s.y; cu[2] = s.z; cu[3] = s.w;
    }
    __syncthreads();
    const float be1 = fminf(fmaxf(pb1[0], 0.f), 1.f);
    const float be2 = fminf(fmaxf(pb2[0], 0.f), 1.f);
    const float be3 = fminf(fmaxf(pb3[0], 0.f), 1.f);
    float2 bias2 = *(const float2*)&b2g[lane * 2];
    float bias3 = (lane < 35) ? b3g[lane] : 0.f;
    float m1[4] = {0.f, 0.f, 0.f, 0.f};
    float m2[2][2] = {{0.f, 0.f}, {0.f, 0.f}};  // [row][j-sub]  (wave0 only)
    float m3[2] = {0.f, 0.f};                    // (wave0 lanes<35 only)
    const int kbase = wv * 128;

    for (int t = 0; t < 25; ++t) {
        // ---- layer-1 LIF (own row, 4 neurons) ----
        float4 s1;
        {
            float r0 = (m1[0] > 1.f) ? 1.f : 0.f;
            float r1 = (m1[1] > 1.f) ? 1.f : 0.f;
            float r2 = (m1[2] > 1.f) ? 1.f : 0.f;
            float r3 = (m1[3] > 1.f) ? 1.f : 0.f;
            m1[0] = fmaf(be1, m1[0], cu[0]) - r0;
            m1[1] = fmaf(be1, m1[1], cu[1]) - r1;
            m1[2] = fmaf(be1, m1[2], cu[2]) - r2;
            m1[3] = fmaf(be1, m1[3], cu[3]) - r3;
            s1.x = (m1[0] > 1.f) ? 1.f : 0.f;
            s1.y = (m1[1] > 1.f) ? 1.f : 0.f;
            s1.z = (m1[2] > 1.f) ? 1.f : 0.f;
            s1.w = (m1[3] > 1.f) ? 1.f : 0.f;
        }
        *(float4*)&spkT[myrow][lane * 4] = s1;
        __syncthreads();                                   // B1
        // ---- fc2 partial: k-half, both rows, j-pair ----
        float a00 = 0.f, a01 = 0.f, a10 = 0.f, a11 = 0.f;
        #pragma unroll 8
        for (int k4 = 0; k4 < 32; ++k4) {
            float4 sr0 = *(const float4*)&spkT[0][kbase + k4 * 4];   // broadcast
            float4 sr1 = *(const float4*)&spkT[1][kbase + k4 * 4];
            const float* wp = &w2T[(kbase + k4 * 4) * 128 + 2 * lane];
            float2 w0 = *(const float2*)(wp);
            float2 w1 = *(const float2*)(wp + 128);
            float2 w2 = *(const float2*)(wp + 256);
            float2 w3 = *(const float2*)(wp + 384);
            a00 = fmaf(sr0.x, w0.x, a00); a01 = fmaf(sr0.x, w0.y, a01);
            a10 = fmaf(sr1.x, w0.x, a10); a11 = fmaf(sr1.x, w0.y, a11);
            a00 = fmaf(sr0.y, w1.x, a00); a01 = fmaf(sr0.y, w1.y, a01);
            a10 = fmaf(sr1.y, w1.x, a10); a11 = fmaf(sr1.y, w1.y, a11);
            a00 = fmaf(sr0.z, w2.x, a00); a01 = fmaf(sr0.z, w2.y, a01);
            a10 = fmaf(sr1.z, w2.x, a10); a11 = fmaf(sr1.z, w2.y, a11);
            a00 = fmaf(sr0.w, w3.x, a00); a01 = fmaf(sr0.w, w3.y, a01);
            a10 = fmaf(sr1.w, w3.x, a10); a11 = fmaf(sr1.w, w3.y, a11);
        }
        if (wv == 1) red[lane] = make_float4(a00, a01, a10, a11);
        __syncthreads();                                   // B2
        // ---- layer-2 LIF (wave0 owns all m2 state) ----
        if (wv == 0) {
            float4 o = red[lane];
            float in00 = a00 + o.x + bias2.x, in01 = a01 + o.y + bias2.y;
            float in10 = a10 + o.z + bias2.x, in11 = a11 + o.w + bias2.y;
            float r00 = (m2[0][0] > 1.f) ? 1.f : 0.f;
            float r01 = (m2[0][1] > 1.f) ? 1.f : 0.f;
            float r10 = (m2[1][0] > 1.f) ? 1.f : 0.f;
            float r11 = (m2[1][1] > 1.f) ? 1.f : 0.f;
            m2[0][0] = fmaf(be2, m2[0][0], in00) - r00;
            m2[0][1] = fmaf(be2, m2[0][1], in01) - r01;
            m2[1][0] = fmaf(be2, m2[1][0], in10) - r10;
            m2[1][1] = fmaf(be2, m2[1][1], in11) - r11;
            float2 sa, sb;
            sa.x = (m2[0][0] > 1.f) ? 1.f : 0.f;
            sa.y = (m2[0][1] > 1.f) ? 1.f : 0.f;
            sb.x = (m2[1][0] > 1.f) ? 1.f : 0.f;
            sb.y = (m2[1][1] > 1.f) ? 1.f : 0.f;
            *(float2*)&spk2T[0][lane * 2] = sa;
            *(float2*)&spk2T[1][lane * 2] = sb;
        }
        __syncthreads();                                   // B3
        // ---- fc3 partial: k-half (64 k), both rows, j = lane (<35) ----
        float a3r0 = 0.f, a3r1 = 0.f;
        if (lane < 35) {
            const int k3 = wv * 64;
            #pragma unroll 4
            for (int k4 = 0; k4 < 16; ++k4) {
                float4 q0 = *(const float4*)&spk2T[0][k3 + k4 * 4];  // broadcast
                float4 q1 = *(const float4*)&spk2T[1][k3 + k4 * 4];
                const float* wp = &w3T[(k3 + k4 * 4) * 36 + lane];
                float wa = wp[0], wb = wp[36], wc = wp[72], wd = wp[108];
                a3r0 = fmaf(q0.x, wa, a3r0); a3r1 = fmaf(q1.x, wa, a3r1);
                a3r0 = fmaf(q0.y, wb, a3r0); a3r1 = fmaf(q1.y, wb, a3r1);
                a3r0 = fmaf(q0.z, wc, a3r0); a3r1 = fmaf(q1.z, wc, a3r1);
                a3r0 = fmaf(q0.w, wd, a3r0); a3r1 = fmaf(q1.w, wd, a3r1);
            }
        }
        if (wv == 1) red3[lane] = make_float2(a3r0, a3r1);
        __syncthreads();                                   // B4
        if (wv == 0 && lane < 35) {
            float2 o = red3[lane];
            float in0 = a3r0 + o.x + bias3;
            float in1 = a3r1 + o.y + bias3;
            float r0 = (m3[0] > 1.f) ? 1.f : 0.f;
            float r1 = (m3[1] > 1.f) ? 1.f : 0.f;
            m3[0] = fmaf(be3, m3[0], in0) - r0;
            m3[1] = fmaf(be3, m3[1], in1) - r1;
            out[((size_t)t * 512 + b0 + 0) * 35 + lane] = (m3[0] > 1.f) ? 1.f : 0.f;
            out[((size_t)t * 512 + b0 + 1) * 35 + lane] = (m3[1] > 1.f) ? 1.f : 0.f;
        }
    }
}

// ---------------- launch ----------------
extern "C" void kernel_launch(void* const* d_in, const int* in_sizes, int n_in,
                              void* d_out, int out_size, void* d_ws, size_t ws_size,
                              hipStream_t stream) {
    const float* x     = (const float*)d_in[0];
    const float* c1w   = (const float*)d_in[1];
    const float* c1b   = (const float*)d_in[2];
    const float* bn1g  = (const float*)d_in[3];
    const float* bn1b  = (const float*)d_in[4];
    const float* bn1m  = (const float*)d_in[5];
    const float* bn1v  = (const float*)d_in[6];
    const float* c2w   = (const float*)d_in[7];
    const float* c2b   = (const float*)d_in[8];
    const float* bn2g  = (const float*)d_in[9];
    const float* bn2b  = (const float*)d_in[10];
    const float* bn2m  = (const float*)d_in[11];
    const float* bn2v  = (const float*)d_in[12];
    const float* fc1w  = (const float*)d_in[13];
    const float* fc1b  = (const float*)d_in[14];
    const float* fc2w  = (const float*)d_in[15];
    const float* fc2b  = (const float*)d_in[16];
    const float* fc3w  = (const float*)d_in[17];
    const float* fc3b  = (const float*)d_in[18];
    const float* beta1 = (const float*)d_in[19];
    const float* beta2 = (const float*)d_in[20];
    const float* beta3 = (const float*)d_in[21];
    float* ws  = (float*)d_ws;
    float* out = (float*)d_out;

    conv1_kernel<<<dim3(512, 5), 256, 0, stream>>>(x, c1w, c1b, bn1g, bn1b, bn1m, bn1v,
                                                   ws + WS_P1);
    conv2_kernel<<<2048, 256, 0, stream>>>(ws + WS_P1, c2w, c2b, bn2g, bn2b, bn2m, bn2v,
                                           ws + WS_FEAT);
    fc1_kernel<<<dim3(4, 2, 32), 256, 0, stream>>>(ws + WS_FEAT, fc1w, ws + WS_PART);
    scan_kernel<<<256, 128, 0, stream>>>(ws + WS_PART, fc1b, fc2w, fc2b, fc3w, fc3b,
                                         beta1, beta2, beta3, out);
}

// Round 4
// 328.038 us; speedup vs baseline: 1.4847x; 1.0637x over previous
//
#include <hip/hip_runtime.h>

// ---------------- workspace layout (floats) ----------------
#define N_P1    (512*16*50*32)          // 13,107,200
#define N_FEAT  (512*12800)             // 6,553,600
#define N_PART  (32*512*256)            // 4,194,304

#define WS_P1    0
#define WS_FEAT  (WS_P1 + N_P1)
#define WS_PART  (WS_FEAT + N_FEAT)
// after conv2 consumes P1, its region is reused for the SNN tail:
#define WS_S1    0                       // 25*512*256 = 3,276,800
#define WS_IN2   3276800                 // 25*512*128 = 1,638,400
#define WS_S2    4915200                 // 25*512*128 = 1,638,400

// ---------------- conv1: mean over T + conv3x3 + bn-fold + relu + pool ----------------
__global__ __launch_bounds__(256) void conv1_kernel(const float* __restrict__ x,
                                                    const float* __restrict__ w1,
                                                    const float* __restrict__ cb1,
                                                    const float* __restrict__ g1,
                                                    const float* __restrict__ bb1,
                                                    const float* __restrict__ m1g,
                                                    const float* __restrict__ v1,
                                                    float* __restrict__ p1) {
    __shared__ float xs[22 * 66];
    __shared__ float w1s[144];
    __shared__ float sh1s[16];
    const int b = blockIdx.x, s = blockIdx.y;
    const int tid = threadIdx.x;
    if (tid < 144) {
        int c = tid / 9;
        float inv = g1[c] * rsqrtf(v1[c] + 1e-5f);
        w1s[tid] = w1[tid] * inv;
    }
    if (tid < 16) {
        float inv = g1[tid] * rsqrtf(v1[tid] + 1e-5f);
        sh1s[tid] = cb1[tid] * inv + bb1[tid] - m1g[tid] * inv;
    }
    if (tid < 44) xs[(tid >> 1) * 66 + (tid & 1) * 65] = 0.f;   // border cols
    const int r0 = s * 20 - 1;
    const size_t TSTR = (size_t)512 * 6400;
    for (int i = tid; i < 22 * 16; i += 256) {
        int lr = i >> 4, cq = i & 15;
        int gr = r0 + lr;
        float4 a0 = make_float4(0.f, 0.f, 0.f, 0.f), a1 = a0, a2 = a0, a3 = a0;
        if (gr >= 0 && gr < 100) {
            const float* px = x + (size_t)b * 6400 + gr * 64 + cq * 4;
            #pragma unroll
            for (int tt = 0; tt < 24; tt += 4) {
                float4 v0 = *(const float4*)(px + (size_t)(tt + 0) * TSTR);
                float4 v1_ = *(const float4*)(px + (size_t)(tt + 1) * TSTR);
                float4 v2_ = *(const float4*)(px + (size_t)(tt + 2) * TSTR);
                float4 v3 = *(const float4*)(px + (size_t)(tt + 3) * TSTR);
                a0.x += v0.x; a0.y += v0.y; a0.z += v0.z; a0.w += v0.w;
                a1.x += v1_.x; a1.y += v1_.y; a1.z += v1_.z; a1.w += v1_.w;
                a2.x += v2_.x; a2.y += v2_.y; a2.z += v2_.z; a2.w += v2_.w;
                a3.x += v3.x; a3.y += v3.y; a3.z += v3.z; a3.w += v3.w;
            }
            float4 v = *(const float4*)(px + (size_t)24 * TSTR);
            a0.x += v.x; a0.y += v.y; a0.z += v.z; a0.w += v.w;
        }
        const float sc = 1.0f / 25.0f;
        float* d = &xs[lr * 66 + 1 + cq * 4];
        d[0] = (a0.x + a1.x + a2.x + a3.x) * sc;
        d[1] = (a0.y + a1.y + a2.y + a3.y) * sc;
        d[2] = (a0.z + a1.z + a2.z + a3.z) * sc;
        d[3] = (a0.w + a1.w + a2.w + a3.w) * sc;
    }
    __syncthreads();
    for (int pos = tid; pos < 320; pos += 256) {
        int phl = pos >> 5, pw = pos & 31;
        int ph = s * 10 + phl;
        float win[4][4];
        #pragma unroll
        for (int a = 0; a < 4; ++a)
            #pragma unroll
            for (int c2 = 0; c2 < 4; ++c2)
                win[a][c2] = xs[(2 * phl + a) * 66 + 2 * pw + c2];
        #pragma unroll 1
        for (int c = 0; c < 16; ++c) {
            float s00 = 0.f, s01 = 0.f, s10 = 0.f, s11 = 0.f;
            #pragma unroll
            for (int dh = 0; dh < 3; ++dh)
                #pragma unroll
                for (int dw = 0; dw < 3; ++dw) {
                    float w = w1s[c * 9 + dh * 3 + dw];
                    s00 = fmaf(win[dh][dw],         w, s00);
                    s01 = fmaf(win[dh][dw + 1],     w, s01);
                    s10 = fmaf(win[dh + 1][dw],     w, s10);
                    s11 = fmaf(win[dh + 1][dw + 1], w, s11);
                }
            float m = fmaxf(fmaxf(s00, s01), fmaxf(s10, s11));
            float val = fmaxf(m + sh1s[c], 0.f);
            p1[(((size_t)b * 16 + c) * 50 + ph) * 32 + pw] = val;
        }
    }
}

// ---------------- conv2: conv3x3(16->32) + bn-fold + relu + pool, zero-waste ----------------
// grid (512, 5): strip = 5 pool rows. block 320 = phl(5 waves) x q(4 col-quarters) x chg(16).
// thread: 2 out-ch, 1 pool row (2 conv rows), 8 conv cols (4 pool cols).
__global__ __launch_bounds__(320) void conv2_kernel(const float* __restrict__ p1,
                                                    const float* __restrict__ w2g,
                                                    const float* __restrict__ cb2,
                                                    const float* __restrict__ g2,
                                                    const float* __restrict__ bb2,
                                                    const float* __restrict__ m2g,
                                                    const float* __restrict__ v2,
                                                    float* __restrict__ feat) {
    __shared__ float ins[16 * 12 * 36];   // [ci][row -1..10][col -1..34]
    __shared__ float wl[16 * 9 * 32];     // [ci][tap][c]
    __shared__ float sh2s[32];
    const int b = blockIdx.x, s = blockIdx.y;
    const int tid = threadIdx.x;
    const int chg = tid & 15, q = (tid >> 4) & 3, phl = tid >> 6;
    const int ph = s * 5 + phl;

    // input strip rows: gr in [s*10-1, s*10+10], 192 (ci,lr) segments
    for (int i = tid; i < 192; i += 320) {
        int ci = i / 12, lr = i - ci * 12;
        int gr = s * 10 - 1 + lr;
        float* dst = &ins[(ci * 12 + lr) * 36];
        if (gr >= 0 && gr < 50) {
            const float* src = p1 + (((size_t)b * 16 + ci) * 50 + gr) * 32;
            float4 v0 = *(const float4*)src;
            dst[0] = 0.f; dst[1] = v0.x; dst[2] = v0.y; dst[3] = v0.z;
            #pragma unroll
            for (int qq = 1; qq < 8; ++qq) {
                float4 v = *(const float4*)(src + 4 * qq - 1);
                *(float4*)(dst + 4 * qq) = v;
            }
            dst[32] = src[31];
            dst[33] = 0.f; dst[34] = 0.f; dst[35] = 0.f;
        } else {
            #pragma unroll
            for (int qq = 0; qq < 9; ++qq) *(float4*)(dst + 4 * qq) = make_float4(0.f, 0.f, 0.f, 0.f);
        }
    }
    // weights transposed + bn-folded
    for (int i = tid; i < 4608; i += 320) {
        int c = i / 144, rem = i - c * 144;
        float inv = g2[c] * rsqrtf(v2[c] + 1e-5f);
        wl[rem * 32 + c] = w2g[i] * inv;
    }
    if (tid < 32) {
        float inv = g2[tid] * rsqrtf(v2[tid] + 1e-5f);
        sh2s[tid] = cb2[tid] * inv + bb2[tid] - m2g[tid] * inv;
    }
    __syncthreads();

    float acc[2][2][8];   // [out-ch][conv-row a][col]
    #pragma unroll
    for (int c = 0; c < 2; ++c)
        #pragma unroll
        for (int a = 0; a < 2; ++a)
            #pragma unroll
            for (int xx = 0; xx < 8; ++xx) acc[c][a][xx] = 0.f;
    const int xb = q * 8;
    #pragma unroll 1
    for (int ci = 0; ci < 16; ++ci) {
        float2 wv[9];
        #pragma unroll
        for (int t = 0; t < 9; ++t)
            wv[t] = *(const float2*)&wl[(ci * 9 + t) * 32 + 2 * chg];
        #pragma unroll
        for (int lr4 = 0; lr4 < 4; ++lr4) {
            const float* row = &ins[(ci * 12 + (2 * phl + lr4)) * 36 + xb];
            float v[10];
            float4 t0 = *(const float4*)&row[0];
            float4 t1 = *(const float4*)&row[4];
            float2 t2 = *(const float2*)&row[8];
            v[0]=t0.x; v[1]=t0.y; v[2]=t0.z; v[3]=t0.w;
            v[4]=t1.x; v[5]=t1.y; v[6]=t1.z; v[7]=t1.w;
            v[8]=t2.x; v[9]=t2.y;
            #pragma unroll
            for (int a = 0; a < 2; ++a) {
                const int dh = lr4 - a;
                if (dh >= 0 && dh <= 2) {
                    #pragma unroll
                    for (int dw = 0; dw < 3; ++dw) {
                        float w0 = wv[dh * 3 + dw].x;
                        float w1 = wv[dh * 3 + dw].y;
                        #pragma unroll
                        for (int xx = 0; xx < 8; ++xx) {
                            acc[0][a][xx] = fmaf(v[xx + dw], w0, acc[0][a][xx]);
                            acc[1][a][xx] = fmaf(v[xx + dw], w1, acc[1][a][xx]);
                        }
                    }
                }
            }
        }
    }
    #pragma unroll
    for (int ch = 0; ch < 2; ++ch) {
        const int c = 2 * chg + ch;
        const float sh = sh2s[c];
        #pragma unroll
        for (int p = 0; p < 4; ++p) {
            float m = fmaxf(fmaxf(acc[ch][0][2 * p], acc[ch][0][2 * p + 1]),
                            fmaxf(acc[ch][1][2 * p], acc[ch][1][2 * p + 1]));
            float val = fmaxf(m + sh, 0.f);
            feat[(((size_t)b * 32 + c) * 25 + ph) * 16 + q * 4 + p] = val;
        }
    }
}

// ---------------- fc1: split-K f32 GEMM, 64x128 tile, 4x8 micro, 512 blocks ----------------
__global__ __launch_bounds__(256) void fc1_kernel(const float* __restrict__ feat,
                                                  const float* __restrict__ w,
                                                  float* __restrict__ part) {
    __shared__ float As[16 * 68];
    __shared__ float Bs[16 * 136];
    const int bx = blockIdx.x, by = blockIdx.y, bz = blockIdx.z;
    const int tid = threadIdx.x;
    const int tm = tid >> 4, tn = tid & 15;
    const int r = tid >> 2, cq = tid & 3;
    const int m0 = bx * 64, n0 = by * 128;
    const size_t aBase = (size_t)(m0 + r) * 12800 + bz * 400 + cq * 4;
    const size_t bBase = (size_t)(n0 + r) * 12800 + bz * 400 + cq * 4;
    float acc[4][8];
    #pragma unroll
    for (int i = 0; i < 4; ++i)
        #pragma unroll
        for (int j = 0; j < 8; ++j) acc[i][j] = 0.f;

    for (int kt = 0; kt < 25; ++kt) {
        float4 a0 = *(const float4*)(feat + aBase + kt * 16);
        float4 b0 = *(const float4*)(w    + bBase + kt * 16);
        float4 b1 = *(const float4*)(w    + bBase + (size_t)64 * 12800 + kt * 16);
        __syncthreads();
        As[(cq * 4 + 0) * 68 + r] = a0.x; As[(cq * 4 + 1) * 68 + r] = a0.y;
        As[(cq * 4 + 2) * 68 + r] = a0.z; As[(cq * 4 + 3) * 68 + r] = a0.w;
        Bs[(cq * 4 + 0) * 136 + r]      = b0.x; Bs[(cq * 4 + 1) * 136 + r]      = b0.y;
        Bs[(cq * 4 + 2) * 136 + r]      = b0.z; Bs[(cq * 4 + 3) * 136 + r]      = b0.w;
        Bs[(cq * 4 + 0) * 136 + 64 + r] = b1.x; Bs[(cq * 4 + 1) * 136 + 64 + r] = b1.y;
        Bs[(cq * 4 + 2) * 136 + 64 + r] = b1.z; Bs[(cq * 4 + 3) * 136 + 64 + r] = b1.w;
        __syncthreads();
        #pragma unroll
        for (int kk = 0; kk < 16; ++kk) {
            float4 av  = *(const float4*)&As[kk * 68 + tm * 4];
            float4 bv0 = *(const float4*)&Bs[kk * 136 + tn * 8];
            float4 bv1 = *(const float4*)&Bs[kk * 136 + tn * 8 + 4];
            float a_[4] = {av.x, av.y, av.z, av.w};
            float b_[8] = {bv0.x, bv0.y, bv0.z, bv0.w, bv1.x, bv1.y, bv1.z, bv1.w};
            #pragma unroll
            for (int i = 0; i < 4; ++i)
                #pragma unroll
                for (int j = 0; j < 8; ++j)
                    acc[i][j] = fmaf(a_[i], b_[j], acc[i][j]);
        }
    }
    #pragma unroll
    for (int i = 0; i < 4; ++i) {
        float* dst = &part[(size_t)bz * 131072 + (size_t)(m0 + tm * 4 + i) * 256 + n0 + tn * 8];
        *(float4*)dst       = make_float4(acc[i][0], acc[i][1], acc[i][2], acc[i][3]);
        *(float4*)(dst + 4) = make_float4(acc[i][4], acc[i][5], acc[i][6], acc[i][7]);
    }
}

// ---------------- lif1: reduce fc1 partials + 25-step m1 scan -> S1 (t,b,k) ----------------
__global__ __launch_bounds__(256) void lif1_kernel(const float* __restrict__ part,
                                                   const float* __restrict__ b1g,
                                                   const float* __restrict__ pb1,
                                                   float* __restrict__ S1) {
    const int i = blockIdx.x * 256 + threadIdx.x;    // 131072 = 512 b x 256 k
    const int k = i & 255;
    float cu = b1g[k];
    #pragma unroll 8
    for (int z = 0; z < 32; ++z) cu += part[(size_t)z * 131072 + i];
    const float be = fminf(fmaxf(pb1[0], 0.f), 1.f);
    float m = 0.f;
    #pragma unroll
    for (int t = 0; t < 25; ++t) {
        float r = (m > 1.f) ? 1.f : 0.f;
        m = fmaf(be, m, cu) - r;
        S1[(size_t)t * 131072 + i] = (m > 1.f) ? 1.f : 0.f;
    }
}

// ---------------- fc2 GEMM: in2(12800,128) = S1(12800,256) @ w2^T + b2 ----------------
// grid 400, block 256, BM=32 BN=128 BK=16, micro 2x8.
__global__ __launch_bounds__(256) void fc2g_kernel(const float* __restrict__ S1,
                                                   const float* __restrict__ w2g,
                                                   const float* __restrict__ b2g,
                                                   float* __restrict__ in2) {
    __shared__ float As[16 * 36];
    __shared__ float Bs[16 * 136];
    const int m0 = blockIdx.x * 32;
    const int tid = threadIdx.x;
    const int tm = tid >> 4, tn = tid & 15;
    float acc[2][8];
    #pragma unroll
    for (int i = 0; i < 2; ++i)
        #pragma unroll
        for (int j = 0; j < 8; ++j) acc[i][j] = 0.f;

    for (int kt = 0; kt < 16; ++kt) {
        float4 av = make_float4(0.f, 0.f, 0.f, 0.f);
        if (tid < 128) {
            int r = tid >> 2, cq = tid & 3;
            av = *(const float4*)&S1[(size_t)(m0 + r) * 256 + kt * 16 + cq * 4];
        }
        int rb = tid >> 1, kb = (tid & 1) * 8;
        float4 bv0 = *(const float4*)&w2g[rb * 256 + kt * 16 + kb];
        float4 bv1 = *(const float4*)&w2g[rb * 256 + kt * 16 + kb + 4];
        __syncthreads();
        if (tid < 128) {
            int r = tid >> 2, cq = tid & 3;
            As[(cq * 4 + 0) * 36 + r] = av.x; As[(cq * 4 + 1) * 36 + r] = av.y;
            As[(cq * 4 + 2) * 36 + r] = av.z; As[(cq * 4 + 3) * 36 + r] = av.w;
        }
        Bs[(kb + 0) * 136 + rb] = bv0.x; Bs[(kb + 1) * 136 + rb] = bv0.y;
        Bs[(kb + 2) * 136 + rb] = bv0.z; Bs[(kb + 3) * 136 + rb] = bv0.w;
        Bs[(kb + 4) * 136 + rb] = bv1.x; Bs[(kb + 5) * 136 + rb] = bv1.y;
        Bs[(kb + 6) * 136 + rb] = bv1.z; Bs[(kb + 7) * 136 + rb] = bv1.w;
        __syncthreads();
        #pragma unroll
        for (int kk = 0; kk < 16; ++kk) {
            float2 a2 = *(const float2*)&As[kk * 36 + tm * 2];
            float4 bv0_ = *(const float4*)&Bs[kk * 136 + tn * 8];
            float4 bv1_ = *(const float4*)&Bs[kk * 136 + tn * 8 + 4];
            float b_[8] = {bv0_.x, bv0_.y, bv0_.z, bv0_.w, bv1_.x, bv1_.y, bv1_.z, bv1_.w};
            #pragma unroll
            for (int j = 0; j < 8; ++j) {
                acc[0][j] = fmaf(a2.x, b_[j], acc[0][j]);
                acc[1][j] = fmaf(a2.y, b_[j], acc[1][j]);
            }
        }
    }
    float4 bb0 = *(const float4*)&b2g[tn * 8];
    float4 bb1 = *(const float4*)&b2g[tn * 8 + 4];
    #pragma unroll
    for (int i = 0; i < 2; ++i) {
        float* dst = &in2[(size_t)(m0 + tm * 2 + i) * 128 + tn * 8];
        *(float4*)dst       = make_float4(acc[i][0] + bb0.x, acc[i][1] + bb0.y,
                                          acc[i][2] + bb0.z, acc[i][3] + bb0.w);
        *(float4*)(dst + 4) = make_float4(acc[i][4] + bb1.x, acc[i][5] + bb1.y,
                                          acc[i][6] + bb1.z, acc[i][7] + bb1.w);
    }
}

// ---------------- lif2: 25-step m2 scan -> S2 ----------------
__global__ __launch_bounds__(256) void lif2_kernel(const float* __restrict__ in2,
                                                   const float* __restrict__ pb2,
                                                   float* __restrict__ S2) {
    const int i = blockIdx.x * 256 + threadIdx.x;    // 65536 = 512 b x 128 j
    const float be = fminf(fmaxf(pb2[0], 0.f), 1.f);
    float m = 0.f;
    #pragma unroll
    for (int t = 0; t < 25; ++t) {
        float r = (m > 1.f) ? 1.f : 0.f;
        m = fmaf(be, m, in2[(size_t)t * 65536 + i]) - r;
        S2[(size_t)t * 65536 + i] = (m > 1.f) ? 1.f : 0.f;
    }
}

// ---------------- fc3 + lif3 + out: one wave per batch row ----------------
__global__ __launch_bounds__(64) void fc3l_kernel(const float* __restrict__ S2,
                                                  const float* __restrict__ w3g,
                                                  const float* __restrict__ b3g,
                                                  const float* __restrict__ pb3,
                                                  float* __restrict__ out) {
    __shared__ float w3T[128 * 36];
    __shared__ float s2row[128];
    const int b = blockIdx.x;
    const int lane = threadIdx.x;
    for (int i = lane; i < 4480; i += 64) {
        int j = i >> 7, k = i & 127;
        w3T[k * 36 + j] = w3g[i];
    }
    const float be = fminf(fmaxf(pb3[0], 0.f), 1.f);
    const float bias = (lane < 35) ? b3g[lane] : 0.f;
    float m = 0.f;
    __syncthreads();
    for (int t = 0; t < 25; ++t) {
        float2 v = *(const float2*)&S2[(size_t)t * 65536 + b * 128 + lane * 2];
        *(float2*)&s2row[lane * 2] = v;
        __syncthreads();
        if (lane < 35) {
            float a = bias;
            #pragma unroll 8
            for (int k = 0; k < 128; ++k)
                a = fmaf(s2row[k], w3T[k * 36 + lane], a);
            float r = (m > 1.f) ? 1.f : 0.f;
            m = fmaf(be, m, a) - r;
            out[((size_t)t * 512 + b) * 35 + lane] = (m > 1.f) ? 1.f : 0.f;
        }
        __syncthreads();
    }
}

// ---------------- launch ----------------
extern "C" void kernel_launch(void* const* d_in, const int* in_sizes, int n_in,
                              void* d_out, int out_size, void* d_ws, size_t ws_size,
                              hipStream_t stream) {
    const float* x     = (const float*)d_in[0];
    const float* c1w   = (const float*)d_in[1];
    const float* c1b   = (const float*)d_in[2];
    const float* bn1g  = (const float*)d_in[3];
    const float* bn1b  = (const float*)d_in[4];
    const float* bn1m  = (const float*)d_in[5];
    const float* bn1v  = (const float*)d_in[6];
    const float* c2w   = (const float*)d_in[7];
    const float* c2b   = (const float*)d_in[8];
    const float* bn2g  = (const float*)d_in[9];
    const float* bn2b  = (const float*)d_in[10];
    const float* bn2m  = (const float*)d_in[11];
    const float* bn2v  = (const float*)d_in[12];
    const float* fc1w  = (const float*)d_in[13];
    const float* fc1b  = (const float*)d_in[14];
    const float* fc2w  = (const float*)d_in[15];
    const float* fc2b  = (const float*)d_in[16];
    const float* fc3w  = (const float*)d_in[17];
    const float* fc3b  = (const float*)d_in[18];
    const float* beta1 = (const float*)d_in[19];
    const float* beta2 = (const float*)d_in[20];
    const float* beta3 = (const float*)d_in[21];
    float* ws  = (float*)d_ws;
    float* out = (float*)d_out;

    conv1_kernel<<<dim3(512, 5), 256, 0, stream>>>(x, c1w, c1b, bn1g, bn1b, bn1m, bn1v,
                                                   ws + WS_P1);
    conv2_kernel<<<dim3(512, 5), 320, 0, stream>>>(ws + WS_P1, c2w, c2b, bn2g, bn2b, bn2m, bn2v,
                                                   ws + WS_FEAT);
    fc1_kernel<<<dim3(8, 2, 32), 256, 0, stream>>>(ws + WS_FEAT, fc1w, ws + WS_PART);
    lif1_kernel<<<512, 256, 0, stream>>>(ws + WS_PART, fc1b, beta1, ws + WS_S1);
    fc2g_kernel<<<400, 256, 0, stream>>>(ws + WS_S1, fc2w, fc2b, ws + WS_IN2);
    lif2_kernel<<<256, 256, 0, stream>>>(ws + WS_IN2, beta2, ws + WS_S2);
    fc3l_kernel<<<512, 64, 0, stream>>>(ws + WS_S2, fc3w, fc3b, beta3, out);
}